// Round 2
// baseline (316.811 us; speedup 1.0000x reference)
//
#include <hip/hip_runtime.h>
#include <hip/hip_bf16.h>

// GCNEncoder: 2-layer GCN, out-degree norm. N=100000, E=1600000, 128->128->64, fp32 I/O.
// R11: agg128 is at a memory-system service ceiling (~7.2 TB/s random 256B gathers; R10's
// 2x MLP was null). Attack the hidden ~245us instead:
//  (a) f2bf: RNE (5 VALU) -> round-half-away (2 VALU); differs only on exact-tie low bits
//      (p~2^-17) -> numerically free.
//  (b) x preconverted fp32->bf16 by EXTRA BLOCKS fused into scatter2 (196 edge blocks left
//      the machine idle); gemm128 loads A as short8 directly: kills ~160 VALU/lane of
//      conversion AND halves A fetch (51.2->25.6 MB). xb aliases out1 (dead until agg128).
//  (c) aggregates grid-stride x4 (12500 -> 3125 blocks).
// Predict: total 302 -> ~265-275us; agg128 ~54us; absmax ~1e-3 unchanged.

typedef __attribute__((ext_vector_type(8))) short short8;
typedef __attribute__((ext_vector_type(4))) float floatx4;

__device__ inline unsigned short f2bf(float f) {
    union { float f; unsigned u; } v; v.f = f;
    return (unsigned short)((v.u + 0x8000u) >> 16);  // round-half-away; ties p~2^-17 vs RNE
}
__device__ inline float bf2f(unsigned b) {
    union { unsigned u; float f; } v; v.u = b << 16;
    return v.f;
}
__device__ inline float bf2f_hi(unsigned b) {
    union { unsigned u; float f; } v; v.u = b & 0xFFFF0000u;
    return v.f;
}

#define NBMAX 512   // max 256-node buckets -> N <= 131072 (src < 2^24 for packing)
#define CAP   8192  // fixed bucket capacity; mean 4092 + <=768 alignment pad -> safe

// ---- W preconvert fp32[k][n] -> bf16[n][k] for both layers; also zeros bucket cursors ----
__global__ __launch_bounds__(256) void convw_kernel(
    const float* __restrict__ W1, const float* __restrict__ W2,
    unsigned short* __restrict__ Wb1, unsigned short* __restrict__ Wb2,
    int* __restrict__ cnt)
{
    int i = blockIdx.x * 256 + threadIdx.x;
    if (i < NBMAX * 32) cnt[i] = 0;  // cnt_d | cnt_s (2 * NBMAX * 16 ints)
    if (i < 128 * 128) {
        int k = i >> 7, n = i & 127;
        Wb1[n * 128 + k] = f2bf(W1[k * 128 + n]);
    }
    i -= 128 * 128;
    if (i >= 0 && i < 128 * 64) {
        int k = i >> 6, n = i & 63;
        Wb2[n * 128 + k] = f2bf(W2[k * 64 + n]);
    }
}

// ---- pass 1: LDS bucket histograms -> reserve runs via global cursors -> scatter ----
// Blocks >= EB instead stream-convert x fp32 -> xb bf16 (fills the idle machine; xb not
// read until gemm128, two dispatches later).
__global__ __launch_bounds__(256) void scatter2_kernel(
    const int* __restrict__ src, const int* __restrict__ dst, int E,
    int* __restrict__ cnt_d, int* __restrict__ cnt_s,   // stride-16 padded cursors
    unsigned* __restrict__ pairs, unsigned char* __restrict__ srcs_b, int NB,
    const float* __restrict__ x, unsigned short* __restrict__ xb, int NF8)
{
    const int EB = (E + 8191) / 8192;
    if ((int)blockIdx.x >= EB) {
        int i = ((int)blockIdx.x - EB) * 256 + threadIdx.x;  // 8-float chunk id
        if (i < NF8) {
            float4 a0 = ((const float4*)x)[(size_t)i * 2];
            float4 a1 = ((const float4*)x)[(size_t)i * 2 + 1];
            uint4 st;
            st.x = (unsigned)f2bf(a0.x) | ((unsigned)f2bf(a0.y) << 16);
            st.y = (unsigned)f2bf(a0.z) | ((unsigned)f2bf(a0.w) << 16);
            st.z = (unsigned)f2bf(a1.x) | ((unsigned)f2bf(a1.y) << 16);
            st.w = (unsigned)f2bf(a1.z) | ((unsigned)f2bf(a1.w) << 16);
            ((uint4*)xb)[i] = st;
        }
        return;
    }
    __shared__ int hd[NBMAX], bd[NBMAX], cd_[NBMAX];
    __shared__ int hs[NBMAX], bs[NBMAX], cs_[NBMAX];
    for (int i = threadIdx.x; i < NB; i += 256) { hd[i] = 0; cd_[i] = 0; hs[i] = 0; cs_[i] = 0; }
    __syncthreads();
    const int e0 = blockIdx.x * 8192;
    const int e1 = min(e0 + 8192, E);
    for (int i = e0 + threadIdx.x; i < e1; i += 256) {
        atomicAdd(&hd[dst[i] >> 8], 1);
        atomicAdd(&hs[src[i] >> 8], 1);
    }
    __syncthreads();
    for (int i = threadIdx.x; i < NB; i += 256) {
        if (hd[i]) bd[i] = atomicAdd(&cnt_d[i * 16], hd[i]);
        if (hs[i]) bs[i] = atomicAdd(&cnt_s[i * 16], hs[i]);
    }
    __syncthreads();
    for (int i = e0 + threadIdx.x; i < e1; i += 256) {
        int sv = src[i], dv = dst[i];
        int b = dv >> 8;
        int slot = atomicAdd(&cd_[b], 1);
        pairs[(size_t)b * CAP + bd[b] + slot] = ((unsigned)(dv & 255) << 24) | (unsigned)sv;
        int b2 = sv >> 8;
        int slot2 = atomicAdd(&cs_[b2], 1);
        srcs_b[(size_t)b2 * CAP + bs[b2] + slot2] = (unsigned char)(sv & 255);
    }
}

// ---- pass 2 (fused): per-bucket dst sort (4-aligned segment starts, pads filled with dummy
//      index N -> zero row) -> sorted_src + (start,end) per node; src hist -> deg_inv ----
__global__ __launch_bounds__(256) void bucket_finalize_kernel(
    const unsigned* __restrict__ pairs, const unsigned char* __restrict__ srcs_b,
    const int* __restrict__ cnt_d, const int* __restrict__ cnt_s,
    int* __restrict__ sorted_src, int2* __restrict__ se,
    float* __restrict__ deg_inv, int N)
{
    const int b = blockIdx.x;
    const int node0 = b << 8;
    const int t = threadIdx.x;
    const size_t base = (size_t)b * CAP;
    __shared__ int hist[256];
    __shared__ int cur[256];
    __shared__ int pre[256];

    const int cd = cnt_d[b * 16];
    hist[t] = 0;
    __syncthreads();
    for (int i = t; i < cd; i += 256)
        atomicAdd(&hist[pairs[base + i] >> 24], 1);
    __syncthreads();
    int v = hist[t];
    int v4 = (v + 3) & ~3;  // 4-edge aligned segments (16B int4 idx loads)
    pre[t] = v4;
    __syncthreads();
    for (int o = 1; o < 256; o <<= 1) {
        int add = (t >= o) ? pre[t - o] : 0;
        __syncthreads();
        pre[t] += add;
        __syncthreads();
    }
    int excl = pre[t] - v4;
    cur[t] = excl;
    if (node0 + t < N) {
        se[node0 + t] = make_int2((int)base + excl, (int)base + excl + v);
        // fill alignment pad with dummy index N (zero row) -> aggregates need no scalar tail
        for (int i = v; i < v4; ++i) sorted_src[base + excl + i] = N;
    }
    __syncthreads();
    for (int i = t; i < cd; i += 256) {
        unsigned p = pairs[base + i];
        int pos = atomicAdd(&cur[p >> 24], 1);
        sorted_src[base + pos] = (int)(p & 0xFFFFFFu);
    }

    __syncthreads();
    hist[t] = 0;
    __syncthreads();
    const int cs = cnt_s[b * 16];
    for (int i = t; i < cs; i += 256)
        atomicAdd(&hist[srcs_b[base + i]], 1);
    __syncthreads();
    if (node0 + t < N) {
        int d = hist[t];
        deg_inv[node0 + t] = 1.0f / (float)(d < 1 ? 1 : d);
    }
}

// ---------------- MFMA GEMM, no LDS: per-lane A fragments straight from global ----------------
// 64 rows/block (4 waves x 16 rows). A always bf16 [M x 128]. SC=1: deg_inv scale in epilogue.
// B = bf16 Wb[n][k], L1/L2-resident. Block 0 zeroes output row M (dummy row for agg pads).
template <int NC, int SC>
__global__ __launch_bounds__(256) void gemm_mfma_kernel(
    const unsigned short* __restrict__ Ab, const unsigned short* __restrict__ Wb,
    const float* __restrict__ scale, unsigned short* __restrict__ Cb, int M)
{
    constexpr int NT = NC / 16;
    const int t = threadIdx.x;
    if (blockIdx.x == 0 && t < NC / 2)
        ((unsigned*)Cb)[(size_t)M * (NC / 2) + t] = 0;  // zero dummy row M
    const int wm = t >> 6;
    const int lane = t & 63;
    const int lm = lane & 15;
    const int lk = (lane >> 4) * 8;

    const int r0 = blockIdx.x * 64 + wm * 16;
    int row = r0 + lm;
    if (row >= M) row = M - 1;  // clamp loads; stores are guarded

    floatx4 acc[NT];
#pragma unroll
    for (int j = 0; j < NT; ++j) acc[j] = (floatx4){0.f, 0.f, 0.f, 0.f};

#pragma unroll
    for (int kk = 0; kk < 4; ++kk) {
        const int kb = kk * 32 + lk;
        short8 af = *(const short8*)&Ab[(size_t)row * 128 + kb];
#pragma unroll
        for (int j = 0; j < NT; ++j) {
            short8 bfr = *(const short8*)&Wb[(size_t)(j * 16 + lm) * 128 + kb];
            acc[j] = __builtin_amdgcn_mfma_f32_16x16x32_bf16(af, bfr, acc[j], 0, 0, 0);
        }
    }

    const int rbase = r0 + (lane >> 4) * 4;
#pragma unroll
    for (int reg = 0; reg < 4; ++reg) {
        int rg = rbase + reg;
        if (rg < M) {
            float di = SC ? scale[rg] : 1.0f;
#pragma unroll
            for (int j = 0; j < NT; ++j)
                Cb[(size_t)rg * NC + j * 16 + lm] = f2bf(SC ? acc[j][reg] * di : acc[j][reg]);
        }
    }
}

// ---------------- aggregate C=128: half-wave/node, uint2 loads, 8-edge unroll + idx prefetch ----------------
// Epilogue: relu(. + b1) * deg_inv -> bf16 (deg_inv of NEXT layer's row folded here).
#define LD128(vv, ii) uint2 vv = *(const uint2*)&val[(size_t)(ii) * 64 + 2 * l]
#define ACC8_128(I0, I1) do { \
    LD128(v0, I0.x); LD128(v1, I0.y); LD128(v2, I0.z); LD128(v3, I0.w); \
    LD128(v4, I1.x); LD128(v5, I1.y); LD128(v6, I1.z); LD128(v7, I1.w); \
    a0 += ((bf2f(v0.x & 0xFFFF) + bf2f(v1.x & 0xFFFF)) + (bf2f(v2.x & 0xFFFF) + bf2f(v3.x & 0xFFFF))) \
        + ((bf2f(v4.x & 0xFFFF) + bf2f(v5.x & 0xFFFF)) + (bf2f(v6.x & 0xFFFF) + bf2f(v7.x & 0xFFFF))); \
    a1 += ((bf2f_hi(v0.x) + bf2f_hi(v1.x)) + (bf2f_hi(v2.x) + bf2f_hi(v3.x))) \
        + ((bf2f_hi(v4.x) + bf2f_hi(v5.x)) + (bf2f_hi(v6.x) + bf2f_hi(v7.x))); \
    a2 += ((bf2f(v0.y & 0xFFFF) + bf2f(v1.y & 0xFFFF)) + (bf2f(v2.y & 0xFFFF) + bf2f(v3.y & 0xFFFF))) \
        + ((bf2f(v4.y & 0xFFFF) + bf2f(v5.y & 0xFFFF)) + (bf2f(v6.y & 0xFFFF) + bf2f(v7.y & 0xFFFF))); \
    a3 += ((bf2f_hi(v0.y) + bf2f_hi(v1.y)) + (bf2f_hi(v2.y) + bf2f_hi(v3.y))) \
        + ((bf2f_hi(v4.y) + bf2f_hi(v5.y)) + (bf2f_hi(v6.y) + bf2f_hi(v7.y))); \
} while (0)
#define ACC4_128(I0) do { \
    LD128(v0, I0.x); LD128(v1, I0.y); LD128(v2, I0.z); LD128(v3, I0.w); \
    a0 += (bf2f(v0.x & 0xFFFF) + bf2f(v1.x & 0xFFFF)) + (bf2f(v2.x & 0xFFFF) + bf2f(v3.x & 0xFFFF)); \
    a1 += (bf2f_hi(v0.x) + bf2f_hi(v1.x)) + (bf2f_hi(v2.x) + bf2f_hi(v3.x)); \
    a2 += (bf2f(v0.y & 0xFFFF) + bf2f(v1.y & 0xFFFF)) + (bf2f(v2.y & 0xFFFF) + bf2f(v3.y & 0xFFFF)); \
    a3 += (bf2f_hi(v0.y) + bf2f_hi(v1.y)) + (bf2f_hi(v2.y) + bf2f_hi(v3.y)); \
} while (0)

__global__ __launch_bounds__(256) void aggregate128_kernel(
    const int2* __restrict__ se, const int* __restrict__ sorted_src,
    const unsigned* __restrict__ val, const float* __restrict__ bias,
    const float* __restrict__ deg_inv, unsigned* __restrict__ outb, int N)
{
    const int hw = threadIdx.x >> 5;
    const int l = threadIdx.x & 31;
    for (int g = 0; g < 4; ++g) {
        int node = blockIdx.x * 32 + g * 8 + hw;
        if (node >= N) continue;
        int2 r = se[node];
        int e = r.x;
        const int end4 = r.x + ((r.y - r.x + 3) & ~3);  // pads -> zero row, safe to include
        float a0 = 0.f, a1 = 0.f, a2 = 0.f, a3 = 0.f;

        if (e + 8 <= end4) {
            int4 i0 = *(const int4*)&sorted_src[e];
            int4 i1 = *(const int4*)&sorted_src[e + 4];
            for (; e + 16 <= end4; e += 8) {
                int4 n0 = *(const int4*)&sorted_src[e + 8];
                int4 n1 = *(const int4*)&sorted_src[e + 12];
                ACC8_128(i0, i1);
                i0 = n0; i1 = n1;
            }
            ACC8_128(i0, i1);
            e += 8;
        }
        if (e < end4) {  // exactly 4 remain (segment length is a multiple of 4)
            int4 i0 = *(const int4*)&sorted_src[e];
            ACC4_128(i0);
        }

        float di = deg_inv[node];
        float4 bv = *(const float4*)&bias[4 * l];
        a0 = fmaxf(a0 + bv.x, 0.f) * di;
        a1 = fmaxf(a1 + bv.y, 0.f) * di;
        a2 = fmaxf(a2 + bv.z, 0.f) * di;
        a3 = fmaxf(a3 + bv.w, 0.f) * di;
        uint2 o;
        o.x = (unsigned)f2bf(a0) | ((unsigned)f2bf(a1) << 16);
        o.y = (unsigned)f2bf(a2) | ((unsigned)f2bf(a3) << 16);
        *(uint2*)&outb[(size_t)node * 64 + 2 * l] = o;
    }
}

// ---------------- aggregate C=64 (bf16 in, fp32 out, +bias): 8-edge unroll + idx prefetch ----------------
#define LD64(vv, ii) unsigned vv = val[(size_t)(ii) * 32 + l]
#define ACC8_64(I0, I1) do { \
    LD64(v0, I0.x); LD64(v1, I0.y); LD64(v2, I0.z); LD64(v3, I0.w); \
    LD64(v4, I1.x); LD64(v5, I1.y); LD64(v6, I1.z); LD64(v7, I1.w); \
    ax += ((bf2f(v0 & 0xFFFF) + bf2f(v1 & 0xFFFF)) + (bf2f(v2 & 0xFFFF) + bf2f(v3 & 0xFFFF))) \
        + ((bf2f(v4 & 0xFFFF) + bf2f(v5 & 0xFFFF)) + (bf2f(v6 & 0xFFFF) + bf2f(v7 & 0xFFFF))); \
    ay += ((bf2f_hi(v0) + bf2f_hi(v1)) + (bf2f_hi(v2) + bf2f_hi(v3))) \
        + ((bf2f_hi(v4) + bf2f_hi(v5)) + (bf2f_hi(v6) + bf2f_hi(v7))); \
} while (0)
#define ACC4_64(I0) do { \
    LD64(v0, I0.x); LD64(v1, I0.y); LD64(v2, I0.z); LD64(v3, I0.w); \
    ax += (bf2f(v0 & 0xFFFF) + bf2f(v1 & 0xFFFF)) + (bf2f(v2 & 0xFFFF) + bf2f(v3 & 0xFFFF)); \
    ay += (bf2f_hi(v0) + bf2f_hi(v1)) + (bf2f_hi(v2) + bf2f_hi(v3)); \
} while (0)

__global__ __launch_bounds__(256) void aggregate64_kernel(
    const int2* __restrict__ se, const int* __restrict__ sorted_src,
    const unsigned* __restrict__ val, const float* __restrict__ bias,
    float* __restrict__ out, int N)
{
    const int hw = threadIdx.x >> 5;
    const int l = threadIdx.x & 31;
    for (int g = 0; g < 4; ++g) {
        int node = blockIdx.x * 32 + g * 8 + hw;
        if (node >= N) continue;
        int2 r = se[node];
        int e = r.x;
        const int end4 = r.x + ((r.y - r.x + 3) & ~3);
        float ax = 0.f, ay = 0.f;

        if (e + 8 <= end4) {
            int4 i0 = *(const int4*)&sorted_src[e];
            int4 i1 = *(const int4*)&sorted_src[e + 4];
            for (; e + 16 <= end4; e += 8) {
                int4 n0 = *(const int4*)&sorted_src[e + 8];
                int4 n1 = *(const int4*)&sorted_src[e + 12];
                ACC8_64(i0, i1);
                i0 = n0; i1 = n1;
            }
            ACC8_64(i0, i1);
            e += 8;
        }
        if (e < end4) {
            int4 i0 = *(const int4*)&sorted_src[e];
            ACC4_64(i0);
        }

        float2 o = make_float2(ax + bias[2 * l], ay + bias[2 * l + 1]);
        *(float2*)&out[(size_t)node * 64 + 2 * l] = o;
    }
}

extern "C" void kernel_launch(void* const* d_in, const int* in_sizes, int n_in,
                              void* d_out, int out_size, void* d_ws, size_t ws_size,
                              hipStream_t stream) {
    const float* x  = (const float*)d_in[0];
    const int*   ei = (const int*)d_in[1];
    const float* W1 = (const float*)d_in[2];
    const float* b1 = (const float*)d_in[3];
    const float* W2 = (const float*)d_in[4];
    const float* b2 = (const float*)d_in[5];
    float* out = (float*)d_out;

    const int N = in_sizes[0] / 128;
    const int E = in_sizes[1] / 2;
    const int* src = ei;
    const int* dst = ei + E;
    const int NB = (N + 255) >> 8;

    char* ws = (char*)d_ws;
    size_t off = 0;
    auto alloc = [&](size_t bytes) {
        void* p = ws + off;
        off = (off + bytes + 255) & ~(size_t)255;
        return p;
    };
    float* deg_inv  = (float*)alloc((size_t)N * 4);
    int2*  se       = (int2*)alloc((size_t)N * 8);
    int*   cnt_d    = (int*)alloc((size_t)NBMAX * 16 * 4 * 2);  // cnt_d | cnt_s adjacent
    int*   cnt_s    = cnt_d + (size_t)NBMAX * 16;
    unsigned short* Wb1 = (unsigned short*)alloc((size_t)128 * 128 * 2);
    unsigned short* Wb2 = (unsigned short*)alloc((size_t)64 * 128 * 2);
    unsigned*      pairs  = (unsigned*)alloc((size_t)NBMAX * CAP * 4);
    unsigned char* srcs_b = (unsigned char*)alloc((size_t)NBMAX * CAP);
    int*   sorted_src = (int*)alloc((size_t)NBMAX * CAP * 4);
    unsigned short* h    = (unsigned short*)alloc((size_t)(N + 1) * 128 * 2);  // +1: zero pad row
    unsigned short* out1 = (unsigned short*)alloc((size_t)N * 128 * 2);
    // xb (N x 128 bf16) aliases out1: xb written in scatter2, last read by gemm128;
    // out1 first written by aggregate128 (after gemm128) -> lifetimes disjoint.
    unsigned short* xb = out1;
    // g ((N+1) x 64 bf16) aliases pairs (dead after bucket_finalize) when it fits
    unsigned short* g = ((size_t)(N + 1) * 128 <= (size_t)NBMAX * CAP * 4)
                            ? (unsigned short*)pairs
                            : (unsigned short*)alloc((size_t)(N + 1) * 64 * 2);

    convw_kernel<<<96, 256, 0, stream>>>(W1, W2, Wb1, Wb2, cnt_d);

    const int EB = (E + 8191) / 8192;
    const int NF8 = (N * 128) / 8;           // 8-float chunks (128 % 8 == 0)
    const int CB = (NF8 + 255) / 256;        // conversion blocks
    scatter2_kernel<<<EB + CB, 256, 0, stream>>>(src, dst, E, cnt_d, cnt_s,
                                                 pairs, srcs_b, NB, x, xb, NF8);
    bucket_finalize_kernel<<<NB, 256, 0, stream>>>(pairs, srcs_b, cnt_d, cnt_s,
                                                   sorted_src, se, deg_inv, N);

    const int gblocks = (N + 63) / 64;
    const int ablocks = (N + 31) / 32;
    // layer 1: h = bf16(di * (xb @ W1)); out1 = bf16(relu(Agg(h)+b1) * di)
    gemm_mfma_kernel<128, 1><<<gblocks, 256, 0, stream>>>(xb, Wb1, deg_inv, h, N);
    aggregate128_kernel<<<ablocks, 256, 0, stream>>>(se, sorted_src, (const unsigned*)h, b1,
                                                     deg_inv, (unsigned*)out1, N);
    // layer 2: g = bf16(out1 @ W2); out = Agg(g) + b2
    gemm_mfma_kernel<64, 0><<<gblocks, 256, 0, stream>>>(out1, Wb2, nullptr, g, N);
    aggregate64_kernel<<<ablocks, 256, 0, stream>>>(se, sorted_src, (const unsigned*)g, b2, out, N);
}